// Round 4
// baseline (522.845 us; speedup 1.0000x reference)
//
#include <hip/hip_runtime.h>
#include <cstdint>
#include <cstddef>
#include <math.h>

typedef __attribute__((ext_vector_type(8))) short short8;
typedef __attribute__((ext_vector_type(4))) float f32x4;
typedef __attribute__((ext_vector_type(4))) unsigned short u16x4;
typedef unsigned short u16;
typedef unsigned int u32;

#define DEVI static __device__ __forceinline__

DEVI float bf2f(u16 u){ union{u32 i; float f;} v; v.i = ((u32)u)<<16; return v.f; }
DEVI u16 f2bf(float x){ union{u32 i; float f;} v; v.f = x; u32 r = v.i + 0x7FFFu + ((v.i>>16)&1u); return (u16)(r>>16); }

DEVI void gload16(const void* g, void* l){
  __builtin_amdgcn_global_load_lds((__attribute__((address_space(1))) void*)g,
                                   (__attribute__((address_space(3))) void*)l, 16, 0, 0);
}

// fp32 -> bf16 (RNE), 4 elems/thread, grid-stride
__global__ __launch_bounds__(256)
void conv_f2b(const f32x4* __restrict__ s, u16x4* __restrict__ d, int n4)
{
  for (int i = blockIdx.x*blockDim.x + threadIdx.x; i < n4; i += gridDim.x*blockDim.x){
    const f32x4 v = s[i];
    u16x4 o;
    o[0] = f2bf(v[0]); o[1] = f2bf(v[1]); o[2] = f2bf(v[2]); o[3] = f2bf(v[3]);
    d[i] = o;
  }
}

// ---------------------------------------------------------------------------
// NT GEMM: C[m,n] = sum_k A[m,k]*B[n,k] + bias[n]; BM=BN=128, BK=32,
// 256 threads (4 waves as 2x2 of 64x64 tiles), mfma_f32_16x16x32_bf16.
// LINEAR LDS (m97 pattern). A,B are bf16; bias/matrices fp32.
// EPI==0: qkv epilogue (bias + SO(2) rotation + scatter q/k/vT as bf16).
// EPI==1: bias + plain fp32 row-major store to OF.
// ---------------------------------------------------------------------------
template<int NDIM, int EPI>
__global__ __launch_bounds__(256, 2)
void gta_gemm(const u16* __restrict__ A, const u16* __restrict__ B,
              const float* __restrict__ bias,
              u16* __restrict__ O0, u16* __restrict__ O1, u16* __restrict__ O2,
              float* __restrict__ OF,
              const float* __restrict__ MQ, const float* __restrict__ MK,
              const float* __restrict__ MV)
{
  constexpr int KD = 768;
  constexpr int NBN = NDIM / 128;
  constexpr int NT = KD / 32;
  __shared__ u16 As[2][128*32];
  __shared__ u16 Bs[2][128*32];

  const int tid = threadIdx.x;
  const int nwg = gridDim.x;                   // multiple of 8 by construction
  const int cpx = nwg >> 3;
  const int bid = blockIdx.x;
  const int swz = (bid & 7)*cpx + (bid >> 3);  // XCD-aware, bijective (nwg%8==0)
  const int bm = swz / NBN, bn = swz % NBN;

  const int lane = tid & 63, w = tid >> 6;
  const int g = lane >> 4, c = lane & 15;
  const int wr = w >> 1, wc = w & 1;

  // staging: 512 16B-chunks per 128x32 tile, 2 per thread; LDS linear.
  const u16* aSrc[2]; const u16* bSrc[2]; int dOff[2];
  #pragma unroll
  for (int i=0;i<2;i++){
    const int cl = i*256 + tid;
    const int row = cl >> 2, cpos = cl & 3;
    aSrc[i] = A + (size_t)(bm*128+row)*KD + cpos*8;
    bSrc[i] = B + (size_t)(bn*128+row)*KD + cpos*8;
    dOff[i] = (i*256 + (tid & ~63))*16;        // wave-uniform base; HW adds lane*16
  }

  auto stage = [&](int buf, int kt){
    #pragma unroll
    for (int i=0;i<2;i++){
      gload16(aSrc[i] + kt*32, (char*)(&As[buf][0]) + dOff[i]);
      gload16(bSrc[i] + kt*32, (char*)(&Bs[buf][0]) + dOff[i]);
    }
  };

  f32x4 acc[4][4] = {};

  stage(0, 0);
  __syncthreads();
  int cur = 0;
  for (int kt=0; kt<NT; ++kt){
    if (kt+1 < NT) stage(cur^1, kt+1);
    const char* ab = (const char*)&As[cur][0];
    const char* bb = (const char*)&Bs[cur][0];
    short8 af[4], bf[4];
    #pragma unroll
    for (int mi=0;mi<4;mi++) af[mi] = *(const short8*)(ab + (wr*64 + mi*16 + c)*64 + g*16);
    #pragma unroll
    for (int ni=0;ni<4;ni++) bf[ni] = *(const short8*)(bb + (wc*64 + ni*16 + c)*64 + g*16);
    #pragma unroll
    for (int mi=0;mi<4;mi++)
      #pragma unroll
      for (int ni=0;ni<4;ni++)
        acc[mi][ni] = __builtin_amdgcn_mfma_f32_16x16x32_bf16(af[mi], bf[ni], acc[mi][ni], 0,0,0);
    __syncthreads();
    cur ^= 1;
  }

  if constexpr (EPI == 0){
    // bias + SO(2) rotation; pair partner (d^1) is the adjacent lane (c^1).
    // q scaled by 1/sqrt(32). Scatter q[head][l][d], k[head][l][d], vT[head][d][l].
    #pragma unroll
    for (int ni=0; ni<4; ni++){
      const int n = bn*128 + wc*64 + ni*16 + c;
      const float bv = bias[n];
      const int X = n / 768;                   // 0=q 1=k 2=v, uniform per frag
      const int nn = n - X*768;
      const int h = nn >> 5, d = nn & 31;
      const int fi = d >> 1, r = d & 1;
      const float* mp = (X==0) ? MQ : ((X==1) ? MK : MV);
      const float qs = (X==0) ? 0.17677669529663687f : 1.0f;
      u16* dst01 = (X==0) ? O0 : O1;
      #pragma unroll
      for (int mi=0; mi<4; mi++){
        #pragma unroll
        for (int j=0; j<4; j++){
          const int m = bm*128 + wr*64 + mi*16 + g*4 + j;
          const int l = m & 1023, bix = m >> 10;
          const float val = acc[mi][ni][j] + bv;
          const float oth = __shfl_xor(val, 1);
          // mat[l][fi][r][0..1], fp32, stride 64 floats per l
          const float2 mrow = *(const float2*)(mp + (size_t)l*64 + fi*4 + r*2);
          const float x0 = r ? oth : val;
          const float x1 = r ? val : oth;
          const float y = (mrow.x*x0 + mrow.y*x1) * qs;
          const int head = bix*24 + h;
          if (X == 2) O2[(size_t)(head*32 + d)*1024 + l] = f2bf(y);
          else        dst01[((size_t)head*1024 + l)*32 + d] = f2bf(y);
        }
      }
    }
  } else {
    #pragma unroll
    for (int ni=0; ni<4; ni++){
      const int n = bn*128 + wc*64 + ni*16 + c;
      const float bv = bias[n];
      #pragma unroll
      for (int mi=0; mi<4; mi++){
        const int mb = bm*128 + wr*64 + mi*16 + g*4;
        #pragma unroll
        for (int j=0; j<4; j++)
          OF[(size_t)(mb+j)*NDIM + n] = acc[mi][ni][j] + bv;
      }
    }
  }
}

// ---------------------------------------------------------------------------
// Flash attention, LDS-free. 384 heads x 8 q-blocks; 4 waves x 32 q-rows.
// Swapped QK^T: mfma(A=K, B=Q) -> D[kv][q] (col=lane&15=q). K/V fragments
// loaded straight from global in fragment order (L2-resident, 8 blocks/head).
// PV permuted-k pairing: P slot (g,e) carries kv-offset
// kperm(g,e) = (e<4 ? 4g+e : 16+4g+(e-4)); V fragment built with same kperm.
// ---------------------------------------------------------------------------
__global__ __launch_bounds__(256, 2)
void gta_attn(const u16* __restrict__ Qm, const u16* __restrict__ Km,
              const u16* __restrict__ Vt, const float* __restrict__ MO,
              u16* __restrict__ AO)
{
  const int tid = threadIdx.x;
  const int bid = blockIdx.x;
  const int nwg = gridDim.x;     // 3072
  const int cpx = nwg >> 3;
  const int swz = (bid & 7)*cpx + (bid >> 3);
  const int head = swz >> 3, qb = swz & 7;

  const int lane = tid & 63, w = tid >> 6;
  const int g = lane >> 4, c = lane & 15;

  const u16* qh = Qm + (size_t)head*32768;   // [l][32]
  const u16* kh = Km + (size_t)head*32768;   // [l][32]
  const u16* vh = Vt + (size_t)head*32768;   // [32][l] (transposed)

  // Q B-fragment: lane (g,c) holds Q[qrow(c)][d = 8g..8g+7]
  short8 qf[2];
  #pragma unroll
  for (int i=0;i<2;i++){
    const int qrow = qb*128 + w*32 + i*16 + c;
    qf[i] = *(const short8*)(qh + (size_t)qrow*32 + g*8);
  }

  f32x4 acc[2][2] = {};
  float mrun[2] = {-INFINITY, -INFINITY};
  float lrun[2] = {0.f, 0.f};
  const f32x4 fz = {0.f, 0.f, 0.f, 0.f};

  for (int t=0; t<32; ++t){                  // 32 kv-slices of 32
    const int kv0 = t*32;
    // K A-fragments: lane (g,c) holds K[kv0(+16) + c][8g..8g+7]
    const short8 ka0 = *(const short8*)(kh + (size_t)(kv0 + c)*32 + g*8);
    const short8 ka1 = *(const short8*)(kh + (size_t)(kv0 + 16 + c)*32 + g*8);
    // V B-fragments with kperm: slots e<4 -> kv0+4g+e ; e>=4 -> kv0+16+4g+(e-4)
    short8 pb[2];
    #pragma unroll
    for (int db=0; db<2; ++db){
      const int d = db*16 + c;
      const u16* vrow = vh + (size_t)d*1024 + kv0;
      const u32* lo = (const u32*)(vrow + 4*g);        // kv0+4g+0..3
      const u32* hi = (const u32*)(vrow + 16 + 4*g);   // kv0+16+4g+0..3
      union{u32 u[4]; short8 s;} uu;
      uu.u[0]=lo[0]; uu.u[1]=lo[1]; uu.u[2]=hi[0]; uu.u[3]=hi[1];
      pb[db]=uu.s;
    }
    #pragma unroll
    for (int qi=0; qi<2; ++qi){
      const f32x4 s0 = __builtin_amdgcn_mfma_f32_16x16x32_bf16(ka0, qf[qi], fz, 0,0,0);
      const f32x4 s1 = __builtin_amdgcn_mfma_f32_16x16x32_bf16(ka1, qf[qi], fz, 0,0,0);
      // lane (g,c): s0[j] = S[kv0+4g+j][q=c], s1[j] = S[kv0+16+4g+j][q=c]
      float mt = fmaxf(fmaxf(fmaxf(s0[0],s0[1]),fmaxf(s0[2],s0[3])),
                       fmaxf(fmaxf(s1[0],s1[1]),fmaxf(s1[2],s1[3])));
      mt = fmaxf(mt, __shfl_xor(mt, 16));
      mt = fmaxf(mt, __shfl_xor(mt, 32));    // uniform over the 4 g-lanes of q=c
      const float mnew = fmaxf(mrun[qi], mt);
      const float sc = __expf(mrun[qi] - mnew);
      mrun[qi] = mnew;
      const float p0 = __expf(s0[0]-mnew), p1 = __expf(s0[1]-mnew);
      const float p2 = __expf(s0[2]-mnew), p3 = __expf(s0[3]-mnew);
      const float p4 = __expf(s1[0]-mnew), p5 = __expf(s1[1]-mnew);
      const float p6 = __expf(s1[2]-mnew), p7 = __expf(s1[3]-mnew);
      lrun[qi] = lrun[qi]*sc + (((p0+p1)+(p2+p3)) + ((p4+p5)+(p6+p7)));
      short8 pa;                              // slot (g,e) = kv0 + kperm(g,e)  ✓ matches pb
      pa[0]=(short)f2bf(p0); pa[1]=(short)f2bf(p1);
      pa[2]=(short)f2bf(p2); pa[3]=(short)f2bf(p3);
      pa[4]=(short)f2bf(p4); pa[5]=(short)f2bf(p5);
      pa[6]=(short)f2bf(p6); pa[7]=(short)f2bf(p7);
      // acc[qi][db][j] = O[q=4g+j][d=db*16+c]; sc for q=4g+j is at lane 4g+j
      const int gb = g*4;
      const float sb0 = __shfl(sc, gb+0), sb1 = __shfl(sc, gb+1);
      const float sb2 = __shfl(sc, gb+2), sb3 = __shfl(sc, gb+3);
      #pragma unroll
      for (int db=0; db<2; ++db){
        f32x4 a = acc[qi][db];
        a[0]*=sb0; a[1]*=sb1; a[2]*=sb2; a[3]*=sb3;
        acc[qi][db] = __builtin_amdgcn_mfma_f32_16x16x32_bf16(pa, pb[db], a, 0,0,0);
      }
    }
  }

  // epilogue: normalize, inverse rotation (mat_o, pre-transposed host-side),
  // store bf16 [b][l][h*32+d]
  const int bix = head / 24, hh = head - bix*24;
  #pragma unroll
  for (int qi=0; qi<2; ++qi){
    float lt = lrun[qi];
    lt += __shfl_xor(lt, 16);
    lt += __shfl_xor(lt, 32);
    const float linv = 1.0f / lt;
    const int gb = g*4;
    const float lb[4] = { __shfl(linv, gb+0), __shfl(linv, gb+1),
                          __shfl(linv, gb+2), __shfl(linv, gb+3) };
    #pragma unroll
    for (int db=0; db<2; ++db){
      const int dh = db*16 + c;
      const int r = dh & 1, fi = dh >> 1;
      #pragma unroll
      for (int j=0; j<4; ++j){
        const float o = acc[qi][db][j] * lb[j];
        const float oth = __shfl_xor(o, 1);   // partner d = dh^1 (lane c^1)
        const int lseq = qb*128 + w*32 + qi*16 + gb + j;
        const float2 mrow = *(const float2*)(MO + (size_t)lseq*64 + fi*4 + r*2);
        const float y = mrow.x*(r ? oth : o) + mrow.y*(r ? o : oth);
        AO[((size_t)(bix*1024 + lseq))*768 + hh*32 + dh] = f2bf(y);
      }
    }
  }
}

extern "C" void kernel_launch(void* const* d_in, const int* in_sizes, int n_in,
                              void* d_out, int out_size, void* d_ws, size_t ws_size,
                              hipStream_t stream)
{
  (void)in_sizes; (void)n_in; (void)out_size; (void)ws_size;
  const float* x    = (const float*)d_in[0];
  const float* Wqkv = (const float*)d_in[1];
  const float* bqkv = (const float*)d_in[2];
  const float* Wo   = (const float*)d_in[3];
  const float* bo   = (const float*)d_in[4];
  const float* mq   = (const float*)d_in[5];
  const float* mk   = (const float*)d_in[6];
  const float* mv   = (const float*)d_in[7];
  const float* mo   = (const float*)d_in[8];
  float* out = (float*)d_out;

  const size_t NX   = (size_t)16*1024*768;     // 12.58M
  const size_t NWQ  = (size_t)2304*768;        // 1.77M
  const size_t NWO  = (size_t)768*768;         // 0.59M
  const size_t SQ   = (size_t)384*1024*32;     // per-tensor q/k/v elements

  // ws layout (~105.5 MB peak; ao aliases xb — xb dead after GEMM1, ao born after)
  u16* xb   = (u16*)d_ws;          // bf16 x            [16384][768]
  u16* wqb  = xb  + NX;            // bf16 W_qkv        [2304][768]
  u16* wob  = wqb + NWQ;           // bf16 W_o          [768][768]
  u16* q_l  = wob + NWO;           // [head][l][32]
  u16* k_l  = q_l + SQ;            // [head][l][32]
  u16* vT   = k_l + SQ;            // [head][32][l]
  u16* ao   = xb;                  // [b*l][768] bf16 (aliases xb)

  hipLaunchKernelGGL(conv_f2b, dim3(2048), dim3(256), 0, stream,
                     (const f32x4*)x, (u16x4*)xb, (int)(NX/4));
  hipLaunchKernelGGL(conv_f2b, dim3(1024), dim3(256), 0, stream,
                     (const f32x4*)Wqkv, (u16x4*)wqb, (int)(NWQ/4));
  hipLaunchKernelGGL(conv_f2b, dim3(512), dim3(256), 0, stream,
                     (const f32x4*)Wo, (u16x4*)wob, (int)(NWO/4));

  hipLaunchKernelGGL((gta_gemm<2304,0>), dim3(2304), dim3(256), 0, stream,
                     xb, wqb, bqkv, q_l, k_l, vT, (float*)nullptr, mq, mk, mv);
  hipLaunchKernelGGL(gta_attn, dim3(3072), dim3(256), 0, stream,
                     q_l, k_l, vT, mo, ao);
  hipLaunchKernelGGL((gta_gemm<768,1>), dim3(768), dim3(256), 0, stream,
                     ao, wob, bo, (u16*)nullptr, (u16*)nullptr, (u16*)nullptr, out,
                     (const float*)nullptr, (const float*)nullptr, (const float*)nullptr);
}

// Round 7
// 516.853 us; speedup vs baseline: 1.0116x; 1.0116x over previous
//
#include <hip/hip_runtime.h>
#include <cstdint>
#include <cstddef>
#include <math.h>

typedef __attribute__((ext_vector_type(8))) short short8;
typedef __attribute__((ext_vector_type(4))) float f32x4;
typedef __attribute__((ext_vector_type(4))) unsigned short u16x4;
typedef unsigned short u16;
typedef unsigned int u32;

#define DEVI static __device__ __forceinline__

#if __has_builtin(__builtin_amdgcn_exp2f)
#define EXP2(x) __builtin_amdgcn_exp2f(x)
#else
#define EXP2(x) exp2f(x)
#endif

DEVI float bf2f(u16 u){ union{u32 i; float f;} v; v.i = ((u32)u)<<16; return v.f; }
DEVI u16 f2bf(float x){ union{u32 i; float f;} v; v.f = x; u32 r = v.i + 0x7FFFu + ((v.i>>16)&1u); return (u16)(r>>16); }

DEVI void gload16(const void* g, void* l){
  __builtin_amdgcn_global_load_lds((__attribute__((address_space(1))) void*)g,
                                   (__attribute__((address_space(3))) void*)l, 16, 0, 0);
}

// fp32 -> bf16 (RNE), 4 elems/thread, grid-stride
__global__ __launch_bounds__(256)
void conv_f2b(const f32x4* __restrict__ s, u16x4* __restrict__ d, int n4)
{
  for (int i = blockIdx.x*blockDim.x + threadIdx.x; i < n4; i += gridDim.x*blockDim.x){
    const f32x4 v = s[i];
    u16x4 o;
    o[0] = f2bf(v[0]); o[1] = f2bf(v[1]); o[2] = f2bf(v[2]); o[3] = f2bf(v[3]);
    d[i] = o;
  }
}

// ---------------------------------------------------------------------------
// NT GEMM: C[m,n] = sum_k A[m,k]*B[n,k] + bias[n]; BM=BN=128, BK=32,
// 256 threads (4 waves as 2x2 of 64x64 tiles), mfma_f32_16x16x32_bf16.
// LINEAR LDS (m97 pattern). A,B are bf16; bias/matrices fp32.
// EPI==0: qkv epilogue (bias + SO(2) rotation + scatter q/k/vT as bf16;
//         q additionally scaled by log2e/sqrt(32) for the exp2-domain softmax).
// EPI==1: bias + plain fp32 row-major store to OF.
// ---------------------------------------------------------------------------
template<int NDIM, int EPI>
__global__ __launch_bounds__(256, 2)
void gta_gemm(const u16* __restrict__ A, const u16* __restrict__ B,
              const float* __restrict__ bias,
              u16* __restrict__ O0, u16* __restrict__ O1, u16* __restrict__ O2,
              float* __restrict__ OF,
              const float* __restrict__ MQ, const float* __restrict__ MK,
              const float* __restrict__ MV)
{
  constexpr int KD = 768;
  constexpr int NBN = NDIM / 128;
  constexpr int NT = KD / 32;
  __shared__ u16 As[2][128*32];
  __shared__ u16 Bs[2][128*32];

  const int tid = threadIdx.x;
  const int nwg = gridDim.x;                   // multiple of 8 by construction
  const int cpx = nwg >> 3;
  const int bid = blockIdx.x;
  const int swz = (bid & 7)*cpx + (bid >> 3);  // XCD-aware, bijective (nwg%8==0)
  const int bm = swz / NBN, bn = swz % NBN;

  const int lane = tid & 63, w = tid >> 6;
  const int g = lane >> 4, c = lane & 15;
  const int wr = w >> 1, wc = w & 1;

  const u16* aSrc[2]; const u16* bSrc[2]; int dOff[2];
  #pragma unroll
  for (int i=0;i<2;i++){
    const int cl = i*256 + tid;
    const int row = cl >> 2, cpos = cl & 3;
    aSrc[i] = A + (size_t)(bm*128+row)*KD + cpos*8;
    bSrc[i] = B + (size_t)(bn*128+row)*KD + cpos*8;
    dOff[i] = (i*256 + (tid & ~63))*16;        // wave-uniform base; HW adds lane*16
  }

  auto stage = [&](int buf, int kt){
    #pragma unroll
    for (int i=0;i<2;i++){
      gload16(aSrc[i] + kt*32, (char*)(&As[buf][0]) + dOff[i]);
      gload16(bSrc[i] + kt*32, (char*)(&Bs[buf][0]) + dOff[i]);
    }
  };

  f32x4 acc[4][4] = {};

  stage(0, 0);
  __syncthreads();
  int cur = 0;
  for (int kt=0; kt<NT; ++kt){
    if (kt+1 < NT) stage(cur^1, kt+1);
    const char* ab = (const char*)&As[cur][0];
    const char* bb = (const char*)&Bs[cur][0];
    short8 af[4], bf[4];
    #pragma unroll
    for (int mi=0;mi<4;mi++) af[mi] = *(const short8*)(ab + (wr*64 + mi*16 + c)*64 + g*16);
    #pragma unroll
    for (int ni=0;ni<4;ni++) bf[ni] = *(const short8*)(bb + (wc*64 + ni*16 + c)*64 + g*16);
    #pragma unroll
    for (int mi=0;mi<4;mi++)
      #pragma unroll
      for (int ni=0;ni<4;ni++)
        acc[mi][ni] = __builtin_amdgcn_mfma_f32_16x16x32_bf16(af[mi], bf[ni], acc[mi][ni], 0,0,0);
    __syncthreads();
    cur ^= 1;
  }

  if constexpr (EPI == 0){
    #pragma unroll
    for (int ni=0; ni<4; ni++){
      const int n = bn*128 + wc*64 + ni*16 + c;
      const float bv = bias[n];
      const int X = n / 768;                   // 0=q 1=k 2=v, uniform per frag
      const int nn = n - X*768;
      const int h = nn >> 5, d = nn & 31;
      const int fi = d >> 1, r = d & 1;
      const float* mp = (X==0) ? MQ : ((X==1) ? MK : MV);
      // q-scale = log2(e)/sqrt(32): softmax done in exp2 domain downstream
      const float qs = (X==0) ? 0.2550348663f : 1.0f;
      u16* dst01 = (X==0) ? O0 : O1;
      #pragma unroll
      for (int mi=0; mi<4; mi++){
        #pragma unroll
        for (int j=0; j<4; j++){
          const int m = bm*128 + wr*64 + mi*16 + g*4 + j;
          const int l = m & 1023, bix = m >> 10;
          const float val = acc[mi][ni][j] + bv;
          const float oth = __shfl_xor(val, 1);
          const float2 mrow = *(const float2*)(mp + (size_t)l*64 + fi*4 + r*2);
          const float x0 = r ? oth : val;
          const float x1 = r ? val : oth;
          const float y = (mrow.x*x0 + mrow.y*x1) * qs;
          const int head = bix*24 + h;
          if (X == 2) O2[(size_t)(head*32 + d)*1024 + l] = f2bf(y);
          else        dst01[((size_t)head*1024 + l)*32 + d] = f2bf(y);
        }
      }
    }
  } else {
    #pragma unroll
    for (int ni=0; ni<4; ni++){
      const int n = bn*128 + wc*64 + ni*16 + c;
      const float bv = bias[n];
      #pragma unroll
      for (int mi=0; mi<4; mi++){
        const int mb = bm*128 + wr*64 + mi*16 + g*4;
        #pragma unroll
        for (int j=0; j<4; j++)
          OF[(size_t)(mb+j)*NDIM + n] = acc[mi][ni][j] + bv;
      }
    }
  }
}

// ---------------------------------------------------------------------------
// Flash attention, LDS-free. 384 heads x 8 q-blocks; 4 waves x 32 q-rows.
// Swapped QK^T: mfma(A=K, B=Q) -> D[kv][q] (col=lane&15=q). K/V fragments
// register-prefetched 1 slice ahead straight from global (L2-resident).
// exp2-domain softmax (log2e folded into q). Defer-max THR=0: skip the
// reduce+rescale when no element exceeds the running max (exact numerics).
// PV permuted-k pairing: P slot (g,e) <-> kv-offset kperm(g,e) =
// (e<4 ? 4g+e : 16+4g+(e-4)); V fragment built with the same kperm.
// ---------------------------------------------------------------------------
__global__ __launch_bounds__(256, 2)
void gta_attn(const u16* __restrict__ Qm, const u16* __restrict__ Km,
              const u16* __restrict__ Vt, const float* __restrict__ MO,
              u16* __restrict__ AO)
{
  const int tid = threadIdx.x;
  const int bid = blockIdx.x;
  const int nwg = gridDim.x;     // 3072
  const int cpx = nwg >> 3;
  const int swz = (bid & 7)*cpx + (bid >> 3);
  const int head = swz >> 3, qb = swz & 7;

  const int lane = tid & 63, w = tid >> 6;
  const int g = lane >> 4, c = lane & 15;

  const u16* qh = Qm + (size_t)head*32768;   // [l][32]
  const u16* kh = Km + (size_t)head*32768;   // [l][32]
  const u16* vh = Vt + (size_t)head*32768;   // [32][l] (transposed)

  short8 qf[2];
  #pragma unroll
  for (int i=0;i<2;i++){
    const int qrow = qb*128 + w*32 + i*16 + c;
    qf[i] = *(const short8*)(qh + (size_t)qrow*32 + g*8);
  }

  auto loadK = [&](int kv0, short8& a0, short8& a1){
    a0 = *(const short8*)(kh + (size_t)(kv0 + c)*32 + g*8);
    a1 = *(const short8*)(kh + (size_t)(kv0 + 16 + c)*32 + g*8);
  };
  auto loadV = [&](int kv0, short8& b0, short8& b1){
    #pragma unroll
    for (int db=0; db<2; ++db){
      const int d = db*16 + c;
      const u16* vrow = vh + (size_t)d*1024 + kv0;
      const u32* lo = (const u32*)(vrow + 4*g);        // kv0+4g+0..3
      const u32* hi = (const u32*)(vrow + 16 + 4*g);   // kv0+16+4g+0..3
      union{u32 u[4]; short8 s;} uu;
      uu.u[0]=lo[0]; uu.u[1]=lo[1]; uu.u[2]=hi[0]; uu.u[3]=hi[1];
      if (db) b1 = uu.s; else b0 = uu.s;
    }
  };

  f32x4 acc[2][2] = {};
  float mrun[2] = {-INFINITY, -INFINITY};
  float lrun[2] = {0.f, 0.f};
  const f32x4 fz = {0.f, 0.f, 0.f, 0.f};

  short8 kc0, kc1, vc0, vc1;
  loadK(0, kc0, kc1);
  loadV(0, vc0, vc1);

  for (int t=0; t<32; ++t){
    const int nxt = ((t+1) & 31) * 32;       // wraps to 0 on last iter (harmless)
    short8 kn0, kn1, vn0, vn1;
    loadK(nxt, kn0, kn1);
    loadV(nxt, vn0, vn1);

    #pragma unroll
    for (int qi=0; qi<2; ++qi){
      const f32x4 s0 = __builtin_amdgcn_mfma_f32_16x16x32_bf16(kc0, qf[qi], fz, 0,0,0);
      const f32x4 s1 = __builtin_amdgcn_mfma_f32_16x16x32_bf16(kc1, qf[qi], fz, 0,0,0);
      // lane (g,c): s0[j] = S2[kv0+4g+j][q=c], s1[j] = S2[kv0+16+4g+j][q=c]
      const float mt8 = fmaxf(fmaxf(fmaxf(s0[0],s0[1]),fmaxf(s0[2],s0[3])),
                              fmaxf(fmaxf(s1[0],s1[1]),fmaxf(s1[2],s1[3])));
      if (__any(mt8 > mrun[qi])) {           // slow path: new running max
        float mt = fmaxf(mt8, __shfl_xor(mt8, 16));
        mt = fmaxf(mt, __shfl_xor(mt, 32));  // uniform over the 4 g-lanes of q=c
        const float mnew = fmaxf(mrun[qi], mt);
        const float sc = EXP2(mrun[qi] - mnew);
        mrun[qi] = mnew;
        lrun[qi] *= sc;
        const int gb = g*4;
        const float sb0 = __shfl(sc, gb+0), sb1 = __shfl(sc, gb+1);
        const float sb2 = __shfl(sc, gb+2), sb3 = __shfl(sc, gb+3);
        #pragma unroll
        for (int db=0; db<2; ++db){
          acc[qi][db][0]*=sb0; acc[qi][db][1]*=sb1;
          acc[qi][db][2]*=sb2; acc[qi][db][3]*=sb3;
        }
      }
      const float m = mrun[qi];
      const float p0 = EXP2(s0[0]-m), p1 = EXP2(s0[1]-m);
      const float p2 = EXP2(s0[2]-m), p3 = EXP2(s0[3]-m);
      const float p4 = EXP2(s1[0]-m), p5 = EXP2(s1[1]-m);
      const float p6 = EXP2(s1[2]-m), p7 = EXP2(s1[3]-m);
      lrun[qi] += (((p0+p1)+(p2+p3)) + ((p4+p5)+(p6+p7)));
      short8 pa;                             // slot (g,e) = kv0 + kperm(g,e), matches vc*
      pa[0]=(short)f2bf(p0); pa[1]=(short)f2bf(p1);
      pa[2]=(short)f2bf(p2); pa[3]=(short)f2bf(p3);
      pa[4]=(short)f2bf(p4); pa[5]=(short)f2bf(p5);
      pa[6]=(short)f2bf(p6); pa[7]=(short)f2bf(p7);
      acc[qi][0] = __builtin_amdgcn_mfma_f32_16x16x32_bf16(pa, vc0, acc[qi][0], 0,0,0);
      acc[qi][1] = __builtin_amdgcn_mfma_f32_16x16x32_bf16(pa, vc1, acc[qi][1], 0,0,0);
    }
    kc0=kn0; kc1=kn1; vc0=vn0; vc1=vn1;
  }

  // epilogue: normalize, inverse rotation (mat_o), store bf16 [b][l][h*32+d]
  const int bix = head / 24, hh = head - bix*24;
  #pragma unroll
  for (int qi=0; qi<2; ++qi){
    float lt = lrun[qi];
    lt += __shfl_xor(lt, 16);
    lt += __shfl_xor(lt, 32);
    const float linv = 1.0f / lt;
    const int gb = g*4;
    const float lb[4] = { __shfl(linv, gb+0), __shfl(linv, gb+1),
                          __shfl(linv, gb+2), __shfl(linv, gb+3) };
    #pragma unroll
    for (int db=0; db<2; ++db){
      const int dh = db*16 + c;
      const int r = dh & 1, fi = dh >> 1;
      #pragma unroll
      for (int j=0; j<4; ++j){
        const float o = acc[qi][db][j] * lb[j];
        const float oth = __shfl_xor(o, 1);   // partner d = dh^1 (lane c^1)
        const int lseq = qb*128 + w*32 + qi*16 + gb + j;
        const float2 mrow = *(const float2*)(MO + (size_t)lseq*64 + fi*4 + r*2);
        const float y = mrow.x*(r ? oth : o) + mrow.y*(r ? o : oth);
        AO[((size_t)(bix*1024 + lseq))*768 + hh*32 + dh] = f2bf(y);
      }
    }
  }
}

extern "C" void kernel_launch(void* const* d_in, const int* in_sizes, int n_in,
                              void* d_out, int out_size, void* d_ws, size_t ws_size,
                              hipStream_t stream)
{
  (void)in_sizes; (void)n_in; (void)out_size; (void)ws_size;
  const float* x    = (const float*)d_in[0];
  const float* Wqkv = (const float*)d_in[1];
  const float* bqkv = (const float*)d_in[2];
  const float* Wo   = (const float*)d_in[3];
  const float* bo   = (const float*)d_in[4];
  const float* mq   = (const float*)d_in[5];
  const float* mk   = (const float*)d_in[6];
  const float* mv   = (const float*)d_in[7];
  const float* mo   = (const float*)d_in[8];
  float* out = (float*)d_out;

  const size_t NX   = (size_t)16*1024*768;     // 12.58M
  const size_t NWQ  = (size_t)2304*768;        // 1.77M
  const size_t NWO  = (size_t)768*768;         // 0.59M
  const size_t SQ   = (size_t)384*1024*32;     // per-tensor q/k/v elements

  // ws layout (~105.5 MB peak; ao aliases xb — xb dead after GEMM1, ao born after)
  u16* xb   = (u16*)d_ws;          // bf16 x            [16384][768]
  u16* wqb  = xb  + NX;            // bf16 W_qkv        [2304][768]
  u16* wob  = wqb + NWQ;           // bf16 W_o          [768][768]
  u16* q_l  = wob + NWO;           // [head][l][32]
  u16* k_l  = q_l + SQ;            // [head][l][32]
  u16* vT   = k_l + SQ;            // [head][32][l]
  u16* ao   = xb;                  // [b*l][768] bf16 (aliases xb)

  hipLaunchKernelGGL(conv_f2b, dim3(2048), dim3(256), 0, stream,
                     (const f32x4*)x, (u16x4*)xb, (int)(NX/4));
  hipLaunchKernelGGL(conv_f2b, dim3(1024), dim3(256), 0, stream,
                     (const f32x4*)Wqkv, (u16x4*)wqb, (int)(NWQ/4));
  hipLaunchKernelGGL(conv_f2b, dim3(512), dim3(256), 0, stream,
                     (const f32x4*)Wo, (u16x4*)wob, (int)(NWO/4));

  hipLaunchKernelGGL((gta_gemm<2304,0>), dim3(2304), dim3(256), 0, stream,
                     xb, wqb, bqkv, q_l, k_l, vT, (float*)nullptr, mq, mk, mv);
  hipLaunchKernelGGL(gta_attn, dim3(3072), dim3(256), 0, stream,
                     q_l, k_l, vT, mo, ao);
  hipLaunchKernelGGL((gta_gemm<768,1>), dim3(768), dim3(256), 0, stream,
                     ao, wob, bo, (u16*)nullptr, (u16*)nullptr, (u16*)nullptr, out,
                     (const float*)nullptr, (const float*)nullptr, (const float*)nullptr);
}

// Round 8
// 515.065 us; speedup vs baseline: 1.0151x; 1.0035x over previous
//
#include <hip/hip_runtime.h>
#include <cstdint>
#include <cstddef>
#include <math.h>

typedef __attribute__((ext_vector_type(8))) short short8;
typedef __attribute__((ext_vector_type(8))) __bf16 bf16x8;
typedef __attribute__((ext_vector_type(4))) float f32x4;
typedef __attribute__((ext_vector_type(4))) unsigned short u16x4;
typedef unsigned short u16;
typedef unsigned int u32;

#define DEVI static __device__ __forceinline__

#if __has_builtin(__builtin_amdgcn_exp2f)
#define EXP2(x) __builtin_amdgcn_exp2f(x)
#else
#define EXP2(x) exp2f(x)
#endif

DEVI float bf2f(u16 u){ union{u32 i; float f;} v; v.i = ((u32)u)<<16; return v.f; }
DEVI u16 f2bf(float x){ union{u32 i; float f;} v; v.f = x; u32 r = v.i + 0x7FFFu + ((v.i>>16)&1u); return (u16)(r>>16); }

DEVI void gload16(const void* g, void* l){
  __builtin_amdgcn_global_load_lds((__attribute__((address_space(1))) void*)g,
                                   (__attribute__((address_space(3))) void*)l, 16, 0, 0);
}

// fp32 -> bf16 (RNE), 4 elems/thread, grid-stride
__global__ __launch_bounds__(256)
void conv_f2b(const f32x4* __restrict__ s, u16x4* __restrict__ d, int n4)
{
  for (int i = blockIdx.x*blockDim.x + threadIdx.x; i < n4; i += gridDim.x*blockDim.x){
    const f32x4 v = s[i];
    u16x4 o;
    o[0] = f2bf(v[0]); o[1] = f2bf(v[1]); o[2] = f2bf(v[2]); o[3] = f2bf(v[3]);
    d[i] = o;
  }
}

// ---------------------------------------------------------------------------
// NT GEMM: C[m,n] = sum_k A[m,k]*B[n,k] + bias[n]; BM=BN=128, BK=32,
// 256 threads (4 waves as 2x2 of 64x64 tiles), mfma_f32_16x16x32_bf16.
// LINEAR LDS (m97 pattern). A,B are bf16; bias/matrices fp32.
// EPI==0: qkv epilogue (bias + SO(2) rotation + scatter q/k/vT as bf16;
//         q additionally scaled by log2e/sqrt(32) for the exp2-domain softmax).
// EPI==1: bias + plain fp32 row-major store to OF.
// ---------------------------------------------------------------------------
template<int NDIM, int EPI>
__global__ __launch_bounds__(256, 2)
void gta_gemm(const u16* __restrict__ A, const u16* __restrict__ B,
              const float* __restrict__ bias,
              u16* __restrict__ O0, u16* __restrict__ O1, u16* __restrict__ O2,
              float* __restrict__ OF,
              const float* __restrict__ MQ, const float* __restrict__ MK,
              const float* __restrict__ MV)
{
  constexpr int KD = 768;
  constexpr int NBN = NDIM / 128;
  constexpr int NT = KD / 32;
  __shared__ u16 As[2][128*32];
  __shared__ u16 Bs[2][128*32];

  const int tid = threadIdx.x;
  const int nwg = gridDim.x;                   // multiple of 8 by construction
  const int cpx = nwg >> 3;
  const int bid = blockIdx.x;
  const int swz = (bid & 7)*cpx + (bid >> 3);  // XCD-aware, bijective (nwg%8==0)
  const int bm = swz / NBN, bn = swz % NBN;

  const int lane = tid & 63, w = tid >> 6;
  const int g = lane >> 4, c = lane & 15;
  const int wr = w >> 1, wc = w & 1;

  const u16* aSrc[2]; const u16* bSrc[2]; int dOff[2];
  #pragma unroll
  for (int i=0;i<2;i++){
    const int cl = i*256 + tid;
    const int row = cl >> 2, cpos = cl & 3;
    aSrc[i] = A + (size_t)(bm*128+row)*KD + cpos*8;
    bSrc[i] = B + (size_t)(bn*128+row)*KD + cpos*8;
    dOff[i] = (i*256 + (tid & ~63))*16;        // wave-uniform base; HW adds lane*16
  }

  auto stage = [&](int buf, int kt){
    #pragma unroll
    for (int i=0;i<2;i++){
      gload16(aSrc[i] + kt*32, (char*)(&As[buf][0]) + dOff[i]);
      gload16(bSrc[i] + kt*32, (char*)(&Bs[buf][0]) + dOff[i]);
    }
  };

  f32x4 acc[4][4] = {};

  stage(0, 0);
  __syncthreads();
  int cur = 0;
  for (int kt=0; kt<NT; ++kt){
    if (kt+1 < NT) stage(cur^1, kt+1);
    const char* ab = (const char*)&As[cur][0];
    const char* bb = (const char*)&Bs[cur][0];
    short8 af[4], bf[4];
    #pragma unroll
    for (int mi=0;mi<4;mi++) af[mi] = *(const short8*)(ab + (wr*64 + mi*16 + c)*64 + g*16);
    #pragma unroll
    for (int ni=0;ni<4;ni++) bf[ni] = *(const short8*)(bb + (wc*64 + ni*16 + c)*64 + g*16);
    #pragma unroll
    for (int mi=0;mi<4;mi++)
      #pragma unroll
      for (int ni=0;ni<4;ni++)
        acc[mi][ni] = __builtin_amdgcn_mfma_f32_16x16x32_bf16(af[mi], bf[ni], acc[mi][ni], 0,0,0);
    __syncthreads();
    cur ^= 1;
  }

  if constexpr (EPI == 0){
    #pragma unroll
    for (int ni=0; ni<4; ni++){
      const int n = bn*128 + wc*64 + ni*16 + c;
      const float bv = bias[n];
      const int X = n / 768;                   // 0=q 1=k 2=v, uniform per frag
      const int nn = n - X*768;
      const int h = nn >> 5, d = nn & 31;
      const int fi = d >> 1, r = d & 1;
      const float* mp = (X==0) ? MQ : ((X==1) ? MK : MV);
      // q-scale = log2(e)/sqrt(32): softmax done in exp2 domain downstream
      const float qs = (X==0) ? 0.2550348663f : 1.0f;
      u16* dst01 = (X==0) ? O0 : O1;
      #pragma unroll
      for (int mi=0; mi<4; mi++){
        #pragma unroll
        for (int j=0; j<4; j++){
          const int m = bm*128 + wr*64 + mi*16 + g*4 + j;
          const int l = m & 1023, bix = m >> 10;
          const float val = acc[mi][ni][j] + bv;
          const float oth = __shfl_xor(val, 1);
          const float2 mrow = *(const float2*)(mp + (size_t)l*64 + fi*4 + r*2);
          const float x0 = r ? oth : val;
          const float x1 = r ? val : oth;
          const float y = (mrow.x*x0 + mrow.y*x1) * qs;
          const int head = bix*24 + h;
          if (X == 2) O2[(size_t)(head*32 + d)*1024 + l] = f2bf(y);
          else        dst01[((size_t)head*1024 + l)*32 + d] = f2bf(y);
        }
      }
    }
  } else {
    #pragma unroll
    for (int ni=0; ni<4; ni++){
      const int n = bn*128 + wc*64 + ni*16 + c;
      const float bv = bias[n];
      #pragma unroll
      for (int mi=0; mi<4; mi++){
        const int mb = bm*128 + wr*64 + mi*16 + g*4;
        #pragma unroll
        for (int j=0; j<4; j++)
          OF[(size_t)(mb+j)*NDIM + n] = acc[mi][ni][j] + bv;
      }
    }
  }
}

// ---------------------------------------------------------------------------
// Flash attention, LDS-free. 384 heads x 8 q-blocks; 4 waves x 32 q-rows.
// Swapped QK^T: mfma(A=K, B=Q) -> D[kv][q] (col=lane&15=q). K/V fragments
// register-prefetched 1 slice ahead straight from global (L2-resident).
// exp2-domain softmax (log2e folded into q). Defer-max THR=0 fast path.
// P-pack via NATIVE __bf16 casts -> v_cvt_pk_bf16_f32 (m240: let the
// compiler emit it; hand emulation was ~40 VALU/slice). setprio around
// MFMA clusters (T5, m191 regime: independent waves, no barriers).
// PV permuted-k pairing: P slot (g,e) <-> kv-offset kperm(g,e) =
// (e<4 ? 4g+e : 16+4g+(e-4)); V fragment built with the same kperm.
// ---------------------------------------------------------------------------
__global__ __launch_bounds__(256, 2)
void gta_attn(const u16* __restrict__ Qm, const u16* __restrict__ Km,
              const u16* __restrict__ Vt, const float* __restrict__ MO,
              u16* __restrict__ AO)
{
  const int tid = threadIdx.x;
  const int bid = blockIdx.x;
  const int nwg = gridDim.x;     // 3072
  const int cpx = nwg >> 3;
  const int swz = (bid & 7)*cpx + (bid >> 3);
  const int head = swz >> 3, qb = swz & 7;

  const int lane = tid & 63, w = tid >> 6;
  const int g = lane >> 4, c = lane & 15;

  const u16* qh = Qm + (size_t)head*32768;   // [l][32]
  const u16* kh = Km + (size_t)head*32768;   // [l][32]
  const u16* vh = Vt + (size_t)head*32768;   // [32][l] (transposed)

  short8 qf[2];
  #pragma unroll
  for (int i=0;i<2;i++){
    const int qrow = qb*128 + w*32 + i*16 + c;
    qf[i] = *(const short8*)(qh + (size_t)qrow*32 + g*8);
  }

  auto loadK = [&](int kv0, short8& a0, short8& a1){
    a0 = *(const short8*)(kh + (size_t)(kv0 + c)*32 + g*8);
    a1 = *(const short8*)(kh + (size_t)(kv0 + 16 + c)*32 + g*8);
  };
  auto loadV = [&](int kv0, short8& b0, short8& b1){
    #pragma unroll
    for (int db=0; db<2; ++db){
      const int d = db*16 + c;
      const u16* vrow = vh + (size_t)d*1024 + kv0;
      const u32* lo = (const u32*)(vrow + 4*g);        // kv0+4g+0..3
      const u32* hi = (const u32*)(vrow + 16 + 4*g);   // kv0+16+4g+0..3
      union{u32 u[4]; short8 s;} uu;
      uu.u[0]=lo[0]; uu.u[1]=lo[1]; uu.u[2]=hi[0]; uu.u[3]=hi[1];
      if (db) b1 = uu.s; else b0 = uu.s;
    }
  };

  f32x4 acc[2][2] = {};
  float mrun[2] = {-INFINITY, -INFINITY};
  float lrun[2] = {0.f, 0.f};
  const f32x4 fz = {0.f, 0.f, 0.f, 0.f};

  short8 kc0, kc1, vc0, vc1;
  loadK(0, kc0, kc1);
  loadV(0, vc0, vc1);

  for (int t=0; t<32; ++t){
    const int nxt = ((t+1) & 31) * 32;       // wraps to 0 on last iter (harmless)
    short8 kn0, kn1, vn0, vn1;
    loadK(nxt, kn0, kn1);
    loadV(nxt, vn0, vn1);

    #pragma unroll
    for (int qi=0; qi<2; ++qi){
      __builtin_amdgcn_s_setprio(1);
      const f32x4 s0 = __builtin_amdgcn_mfma_f32_16x16x32_bf16(kc0, qf[qi], fz, 0,0,0);
      const f32x4 s1 = __builtin_amdgcn_mfma_f32_16x16x32_bf16(kc1, qf[qi], fz, 0,0,0);
      __builtin_amdgcn_s_setprio(0);
      // lane (g,c): s0[j] = S2[kv0+4g+j][q=c], s1[j] = S2[kv0+16+4g+j][q=c]
      // left-fold: clang fuses nested fmaxf chains into v_max3_f32 (T17)
      const float mt8 = fmaxf(fmaxf(fmaxf(fmaxf(fmaxf(fmaxf(fmaxf(
                        s0[0],s0[1]),s0[2]),s0[3]),s1[0]),s1[1]),s1[2]),s1[3]);
      if (__any(mt8 > mrun[qi])) {           // slow path: new running max
        float mt = fmaxf(mt8, __shfl_xor(mt8, 16));
        mt = fmaxf(mt, __shfl_xor(mt, 32));  // uniform over the 4 g-lanes of q=c
        const float mnew = fmaxf(mrun[qi], mt);
        const float sc = EXP2(mrun[qi] - mnew);
        mrun[qi] = mnew;
        lrun[qi] *= sc;
        const int gb = g*4;
        const float sb0 = __shfl(sc, gb+0), sb1 = __shfl(sc, gb+1);
        const float sb2 = __shfl(sc, gb+2), sb3 = __shfl(sc, gb+3);
        #pragma unroll
        for (int db=0; db<2; ++db){
          acc[qi][db][0]*=sb0; acc[qi][db][1]*=sb1;
          acc[qi][db][2]*=sb2; acc[qi][db][3]*=sb3;
        }
      }
      const float m = mrun[qi];
      const float p0 = EXP2(s0[0]-m), p1 = EXP2(s0[1]-m);
      const float p2 = EXP2(s0[2]-m), p3 = EXP2(s0[3]-m);
      const float p4 = EXP2(s1[0]-m), p5 = EXP2(s1[1]-m);
      const float p6 = EXP2(s1[2]-m), p7 = EXP2(s1[3]-m);
      lrun[qi] += (((p0+p1)+(p2+p3)) + ((p4+p5)+(p6+p7)));
      // native casts -> v_cvt_pk_bf16_f32 pairs (compiler-scheduled)
      bf16x8 pv;
      pv[0]=(__bf16)p0; pv[1]=(__bf16)p1; pv[2]=(__bf16)p2; pv[3]=(__bf16)p3;
      pv[4]=(__bf16)p4; pv[5]=(__bf16)p5; pv[6]=(__bf16)p6; pv[7]=(__bf16)p7;
      const short8 pa = __builtin_bit_cast(short8, pv);
      __builtin_amdgcn_s_setprio(1);
      acc[qi][0] = __builtin_amdgcn_mfma_f32_16x16x32_bf16(pa, vc0, acc[qi][0], 0,0,0);
      acc[qi][1] = __builtin_amdgcn_mfma_f32_16x16x32_bf16(pa, vc1, acc[qi][1], 0,0,0);
      __builtin_amdgcn_s_setprio(0);
    }
    kc0=kn0; kc1=kn1; vc0=vn0; vc1=vn1;
  }

  // epilogue: normalize, inverse rotation (mat_o), store bf16 [b][l][h*32+d]
  const int bix = head / 24, hh = head - bix*24;
  #pragma unroll
  for (int qi=0; qi<2; ++qi){
    float lt = lrun[qi];
    lt += __shfl_xor(lt, 16);
    lt += __shfl_xor(lt, 32);
    const float linv = 1.0f / lt;
    const int gb = g*4;
    const float lb[4] = { __shfl(linv, gb+0), __shfl(linv, gb+1),
                          __shfl(linv, gb+2), __shfl(linv, gb+3) };
    #pragma unroll
    for (int db=0; db<2; ++db){
      const int dh = db*16 + c;
      const int r = dh & 1, fi = dh >> 1;
      #pragma unroll
      for (int j=0; j<4; ++j){
        const float o = acc[qi][db][j] * lb[j];
        const float oth = __shfl_xor(o, 1);   // partner d = dh^1 (lane c^1)
        const int lseq = qb*128 + w*32 + qi*16 + gb + j;
        const float2 mrow = *(const float2*)(MO + (size_t)lseq*64 + fi*4 + r*2);
        const float y = mrow.x*(r ? oth : o) + mrow.y*(r ? o : oth);
        AO[((size_t)(bix*1024 + lseq))*768 + hh*32 + dh] = f2bf(y);
      }
    }
  }
}

extern "C" void kernel_launch(void* const* d_in, const int* in_sizes, int n_in,
                              void* d_out, int out_size, void* d_ws, size_t ws_size,
                              hipStream_t stream)
{
  (void)in_sizes; (void)n_in; (void)out_size; (void)ws_size;
  const float* x    = (const float*)d_in[0];
  const float* Wqkv = (const float*)d_in[1];
  const float* bqkv = (const float*)d_in[2];
  const float* Wo   = (const float*)d_in[3];
  const float* bo   = (const float*)d_in[4];
  const float* mq   = (const float*)d_in[5];
  const float* mk   = (const float*)d_in[6];
  const float* mv   = (const float*)d_in[7];
  const float* mo   = (const float*)d_in[8];
  float* out = (float*)d_out;

  const size_t NX   = (size_t)16*1024*768;     // 12.58M
  const size_t NWQ  = (size_t)2304*768;        // 1.77M
  const size_t NWO  = (size_t)768*768;         // 0.59M
  const size_t SQ   = (size_t)384*1024*32;     // per-tensor q/k/v elements

  // ws layout (~105.5 MB peak; ao aliases xb — xb dead after GEMM1, ao born after)
  u16* xb   = (u16*)d_ws;          // bf16 x            [16384][768]
  u16* wqb  = xb  + NX;            // bf16 W_qkv        [2304][768]
  u16* wob  = wqb + NWQ;           // bf16 W_o          [768][768]
  u16* q_l  = wob + NWO;           // [head][l][32]
  u16* k_l  = q_l + SQ;            // [head][l][32]
  u16* vT   = k_l + SQ;            // [head][32][l]
  u16* ao   = xb;                  // [b*l][768] bf16 (aliases xb)

  hipLaunchKernelGGL(conv_f2b, dim3(2048), dim3(256), 0, stream,
                     (const f32x4*)x, (u16x4*)xb, (int)(NX/4));
  hipLaunchKernelGGL(conv_f2b, dim3(1024), dim3(256), 0, stream,
                     (const f32x4*)Wqkv, (u16x4*)wqb, (int)(NWQ/4));
  hipLaunchKernelGGL(conv_f2b, dim3(512), dim3(256), 0, stream,
                     (const f32x4*)Wo, (u16x4*)wob, (int)(NWO/4));

  hipLaunchKernelGGL((gta_gemm<2304,0>), dim3(2304), dim3(256), 0, stream,
                     xb, wqb, bqkv, q_l, k_l, vT, (float*)nullptr, mq, mk, mv);
  hipLaunchKernelGGL(gta_attn, dim3(3072), dim3(256), 0, stream,
                     q_l, k_l, vT, mo, ao);
  hipLaunchKernelGGL((gta_gemm<768,1>), dim3(768), dim3(256), 0, stream,
                     ao, wob, bo, (u16*)nullptr, (u16*)nullptr, (u16*)nullptr, out,
                     (const float*)nullptr, (const float*)nullptr, (const float*)nullptr);
}

// Round 10
// 510.379 us; speedup vs baseline: 1.0244x; 1.0092x over previous
//
#include <hip/hip_runtime.h>
#include <cstdint>
#include <cstddef>
#include <math.h>

typedef __attribute__((ext_vector_type(8))) short short8;
typedef __attribute__((ext_vector_type(8))) __bf16 bf16x8;
typedef __attribute__((ext_vector_type(4))) float f32x4;
typedef __attribute__((ext_vector_type(4))) unsigned short u16x4;
typedef unsigned short u16;
typedef unsigned int u32;

#define DEVI static __device__ __forceinline__

#if __has_builtin(__builtin_amdgcn_exp2f)
#define EXP2(x) __builtin_amdgcn_exp2f(x)
#else
#define EXP2(x) exp2f(x)
#endif

DEVI float bf2f(u16 u){ union{u32 i; float f;} v; v.i = ((u32)u)<<16; return v.f; }
DEVI u16 f2bf(float x){ union{u32 i; float f;} v; v.f = x; u32 r = v.i + 0x7FFFu + ((v.i>>16)&1u); return (u16)(r>>16); }

DEVI void gload16(const void* g, void* l){
  __builtin_amdgcn_global_load_lds((__attribute__((address_space(1))) void*)g,
                                   (__attribute__((address_space(3))) void*)l, 16, 0, 0);
}

// fp32 -> bf16 (RNE), 4 elems/thread, grid-stride
__global__ __launch_bounds__(256)
void conv_f2b(const f32x4* __restrict__ s, u16x4* __restrict__ d, int n4)
{
  for (int i = blockIdx.x*blockDim.x + threadIdx.x; i < n4; i += gridDim.x*blockDim.x){
    const f32x4 v = s[i];
    u16x4 o;
    o[0] = f2bf(v[0]); o[1] = f2bf(v[1]); o[2] = f2bf(v[2]); o[3] = f2bf(v[3]);
    d[i] = o;
  }
}

// ---------------------------------------------------------------------------
// NT GEMM: C[m,n] = sum_k A[m,k]*B[n,k] + bias[n]; BM=BN=128, BK=32,
// 256 threads (4 waves as 2x2 of 64x64 tiles), mfma_f32_16x16x32_bf16.
// LINEAR LDS (m97 pattern). A,B are bf16; bias/matrices fp32.
// EPI==0: qkv epilogue (bias + SO(2) rotation + scatter q/k/vT as bf16;
//         q additionally scaled by log2e/sqrt(32) for the exp2-domain softmax).
// EPI==1: bias + plain fp32 row-major store to OF.
// ---------------------------------------------------------------------------
template<int NDIM, int EPI>
__global__ __launch_bounds__(256, 2)
void gta_gemm(const u16* __restrict__ A, const u16* __restrict__ B,
              const float* __restrict__ bias,
              u16* __restrict__ O0, u16* __restrict__ O1, u16* __restrict__ O2,
              float* __restrict__ OF,
              const float* __restrict__ MQ, const float* __restrict__ MK,
              const float* __restrict__ MV)
{
  constexpr int KD = 768;
  constexpr int NBN = NDIM / 128;
  constexpr int NT = KD / 32;
  __shared__ u16 As[2][128*32];
  __shared__ u16 Bs[2][128*32];

  const int tid = threadIdx.x;
  const int nwg = gridDim.x;                   // multiple of 8 by construction
  const int cpx = nwg >> 3;
  const int bid = blockIdx.x;
  const int swz = (bid & 7)*cpx + (bid >> 3);  // XCD-aware, bijective (nwg%8==0)
  const int bm = swz / NBN, bn = swz % NBN;

  const int lane = tid & 63, w = tid >> 6;
  const int g = lane >> 4, c = lane & 15;
  const int wr = w >> 1, wc = w & 1;

  const u16* aSrc[2]; const u16* bSrc[2]; int dOff[2];
  #pragma unroll
  for (int i=0;i<2;i++){
    const int cl = i*256 + tid;
    const int row = cl >> 2, cpos = cl & 3;
    aSrc[i] = A + (size_t)(bm*128+row)*KD + cpos*8;
    bSrc[i] = B + (size_t)(bn*128+row)*KD + cpos*8;
    dOff[i] = (i*256 + (tid & ~63))*16;        // wave-uniform base; HW adds lane*16
  }

  auto stage = [&](int buf, int kt){
    #pragma unroll
    for (int i=0;i<2;i++){
      gload16(aSrc[i] + kt*32, (char*)(&As[buf][0]) + dOff[i]);
      gload16(bSrc[i] + kt*32, (char*)(&Bs[buf][0]) + dOff[i]);
    }
  };

  f32x4 acc[4][4] = {};

  stage(0, 0);
  __syncthreads();
  int cur = 0;
  for (int kt=0; kt<NT; ++kt){
    if (kt+1 < NT) stage(cur^1, kt+1);
    const char* ab = (const char*)&As[cur][0];
    const char* bb = (const char*)&Bs[cur][0];
    short8 af[4], bf[4];
    #pragma unroll
    for (int mi=0;mi<4;mi++) af[mi] = *(const short8*)(ab + (wr*64 + mi*16 + c)*64 + g*16);
    #pragma unroll
    for (int ni=0;ni<4;ni++) bf[ni] = *(const short8*)(bb + (wc*64 + ni*16 + c)*64 + g*16);
    #pragma unroll
    for (int mi=0;mi<4;mi++)
      #pragma unroll
      for (int ni=0;ni<4;ni++)
        acc[mi][ni] = __builtin_amdgcn_mfma_f32_16x16x32_bf16(af[mi], bf[ni], acc[mi][ni], 0,0,0);
    __syncthreads();
    cur ^= 1;
  }

  if constexpr (EPI == 0){
    #pragma unroll
    for (int ni=0; ni<4; ni++){
      const int n = bn*128 + wc*64 + ni*16 + c;
      const float bv = bias[n];
      const int X = n / 768;                   // 0=q 1=k 2=v, uniform per frag
      const int nn = n - X*768;
      const int h = nn >> 5, d = nn & 31;
      const int fi = d >> 1, r = d & 1;
      const float* mp = (X==0) ? MQ : ((X==1) ? MK : MV);
      // q-scale = log2(e)/sqrt(32): softmax done in exp2 domain downstream
      const float qs = (X==0) ? 0.2550348663f : 1.0f;
      u16* dst01 = (X==0) ? O0 : O1;
      #pragma unroll
      for (int mi=0; mi<4; mi++){
        #pragma unroll
        for (int j=0; j<4; j++){
          const int m = bm*128 + wr*64 + mi*16 + g*4 + j;
          const int l = m & 1023, bix = m >> 10;
          const float val = acc[mi][ni][j] + bv;
          const float oth = __shfl_xor(val, 1);
          const float2 mrow = *(const float2*)(mp + (size_t)l*64 + fi*4 + r*2);
          const float x0 = r ? oth : val;
          const float x1 = r ? val : oth;
          const float y = (mrow.x*x0 + mrow.y*x1) * qs;
          const int head = bix*24 + h;
          if (X == 2) O2[(size_t)(head*32 + d)*1024 + l] = f2bf(y);
          else        dst01[((size_t)head*1024 + l)*32 + d] = f2bf(y);
        }
      }
    }
  } else {
    #pragma unroll
    for (int ni=0; ni<4; ni++){
      const int n = bn*128 + wc*64 + ni*16 + c;
      const float bv = bias[n];
      #pragma unroll
      for (int mi=0; mi<4; mi++){
        const int mb = bm*128 + wr*64 + mi*16 + g*4;
        #pragma unroll
        for (int j=0; j<4; j++)
          OF[(size_t)(mb+j)*NDIM + n] = acc[mi][ni][j] + bv;
      }
    }
  }
}

// ---------------------------------------------------------------------------
// Flash attention, LDS-free. 3072 (head,qb) units on 1536 blocks; each wave
// sequentially runs 2 units (same head, adjacent qb -> K/V L2/L1-hot on the
// second pass). 1536 blocks = 6 blocks/CU uniformly resident, tail-free
// (fix for the 1.5-dispatch-pass occupancy ramp measured in r8: Occ 52%).
// Per unit: swapped QK^T mfma(K,Q) -> D[kv][q]; 1-deep K/V reg prefetch;
// exp2-domain softmax (log2e folded into q); defer-max THR=0 fast path;
// native-__bf16 P-pack (v_cvt_pk_bf16_f32); setprio around MFMA clusters.
// PV permuted-k pairing: P slot (g,e) <-> kperm(g,e) = (e<4?4g+e:16+4g+e-4);
// V fragment built with the same kperm.
// ---------------------------------------------------------------------------
__global__ __launch_bounds__(256, 2)
void gta_attn(const u16* __restrict__ Qm, const u16* __restrict__ Km,
              const u16* __restrict__ Vt, const float* __restrict__ MO,
              u16* __restrict__ AO)
{
  const int tid = threadIdx.x;
  const int bid = blockIdx.x;
  const int nwg = gridDim.x;     // 1536
  const int cpx = nwg >> 3;
  const int swz = (bid & 7)*cpx + (bid >> 3);

  const int lane = tid & 63, w = tid >> 6;
  const int g = lane >> 4, c = lane & 15;

  for (int ui = 0; ui < 2; ++ui){
    const int u = swz*2 + ui;                // unit id: same head for ui=0,1
    const int head = u >> 3, qb = u & 7;

    const u16* qh = Qm + (size_t)head*32768;   // [l][32]
    const u16* kh = Km + (size_t)head*32768;   // [l][32]
    const u16* vh = Vt + (size_t)head*32768;   // [32][l] (transposed)

    short8 qf[2];
    #pragma unroll
    for (int i=0;i<2;i++){
      const int qrow = qb*128 + w*32 + i*16 + c;
      qf[i] = *(const short8*)(qh + (size_t)qrow*32 + g*8);
    }

    auto loadK = [&](int kv0, short8& a0, short8& a1){
      a0 = *(const short8*)(kh + (size_t)(kv0 + c)*32 + g*8);
      a1 = *(const short8*)(kh + (size_t)(kv0 + 16 + c)*32 + g*8);
    };
    auto loadV = [&](int kv0, short8& b0, short8& b1){
      #pragma unroll
      for (int db=0; db<2; ++db){
        const int d = db*16 + c;
        const u16* vrow = vh + (size_t)d*1024 + kv0;
        const u32* lo = (const u32*)(vrow + 4*g);        // kv0+4g+0..3
        const u32* hi = (const u32*)(vrow + 16 + 4*g);   // kv0+16+4g+0..3
        union{u32 uu4[4]; short8 s;} uu;
        uu.uu4[0]=lo[0]; uu.uu4[1]=lo[1]; uu.uu4[2]=hi[0]; uu.uu4[3]=hi[1];
        if (db) b1 = uu.s; else b0 = uu.s;
      }
    };

    f32x4 acc[2][2] = {};
    float mrun[2] = {-INFINITY, -INFINITY};
    float lrun[2] = {0.f, 0.f};
    const f32x4 fz = {0.f, 0.f, 0.f, 0.f};

    short8 kc0, kc1, vc0, vc1;
    loadK(0, kc0, kc1);
    loadV(0, vc0, vc1);

    for (int t=0; t<32; ++t){
      const int nxt = ((t+1) & 31) * 32;     // wraps to 0 on last iter (harmless)
      short8 kn0, kn1, vn0, vn1;
      loadK(nxt, kn0, kn1);
      loadV(nxt, vn0, vn1);

      #pragma unroll
      for (int qi=0; qi<2; ++qi){
        __builtin_amdgcn_s_setprio(1);
        const f32x4 s0 = __builtin_amdgcn_mfma_f32_16x16x32_bf16(kc0, qf[qi], fz, 0,0,0);
        const f32x4 s1 = __builtin_amdgcn_mfma_f32_16x16x32_bf16(kc1, qf[qi], fz, 0,0,0);
        __builtin_amdgcn_s_setprio(0);
        // lane (g,c): s0[j] = S2[kv0+4g+j][q=c], s1[j] = S2[kv0+16+4g+j][q=c]
        const float mt8 = fmaxf(fmaxf(fmaxf(fmaxf(fmaxf(fmaxf(fmaxf(
                          s0[0],s0[1]),s0[2]),s0[3]),s1[0]),s1[1]),s1[2]),s1[3]);
        if (__any(mt8 > mrun[qi])) {         // slow path: new running max
          float mt = fmaxf(mt8, __shfl_xor(mt8, 16));
          mt = fmaxf(mt, __shfl_xor(mt, 32));
          const float mnew = fmaxf(mrun[qi], mt);
          const float sc = EXP2(mrun[qi] - mnew);
          mrun[qi] = mnew;
          lrun[qi] *= sc;
          const int gb = g*4;
          const float sb0 = __shfl(sc, gb+0), sb1 = __shfl(sc, gb+1);
          const float sb2 = __shfl(sc, gb+2), sb3 = __shfl(sc, gb+3);
          #pragma unroll
          for (int db=0; db<2; ++db){
            acc[qi][db][0]*=sb0; acc[qi][db][1]*=sb1;
            acc[qi][db][2]*=sb2; acc[qi][db][3]*=sb3;
          }
        }
        const float m = mrun[qi];
        const float p0 = EXP2(s0[0]-m), p1 = EXP2(s0[1]-m);
        const float p2 = EXP2(s0[2]-m), p3 = EXP2(s0[3]-m);
        const float p4 = EXP2(s1[0]-m), p5 = EXP2(s1[1]-m);
        const float p6 = EXP2(s1[2]-m), p7 = EXP2(s1[3]-m);
        lrun[qi] += (((p0+p1)+(p2+p3)) + ((p4+p5)+(p6+p7)));
        // native casts -> v_cvt_pk_bf16_f32 pairs (compiler-scheduled)
        bf16x8 pv;
        pv[0]=(__bf16)p0; pv[1]=(__bf16)p1; pv[2]=(__bf16)p2; pv[3]=(__bf16)p3;
        pv[4]=(__bf16)p4; pv[5]=(__bf16)p5; pv[6]=(__bf16)p6; pv[7]=(__bf16)p7;
        const short8 pa = __builtin_bit_cast(short8, pv);
        __builtin_amdgcn_s_setprio(1);
        acc[qi][0] = __builtin_amdgcn_mfma_f32_16x16x32_bf16(pa, vc0, acc[qi][0], 0,0,0);
        acc[qi][1] = __builtin_amdgcn_mfma_f32_16x16x32_bf16(pa, vc1, acc[qi][1], 0,0,0);
        __builtin_amdgcn_s_setprio(0);
      }
      kc0=kn0; kc1=kn1; vc0=vn0; vc1=vn1;
    }

    // epilogue: normalize, inverse rotation (mat_o), store bf16 [b][l][h*32+d]
    const int bix = head / 24, hh = head - bix*24;
    #pragma unroll
    for (int qi=0; qi<2; ++qi){
      float lt = lrun[qi];
      lt += __shfl_xor(lt, 16);
      lt += __shfl_xor(lt, 32);
      const float linv = 1.0f / lt;
      const int gb = g*4;
      const float lb[4] = { __shfl(linv, gb+0), __shfl(linv, gb+1),
                            __shfl(linv, gb+2), __shfl(linv, gb+3) };
      #pragma unroll
      for (int db=0; db<2; ++db){
        const int dh = db*16 + c;
        const int r = dh & 1, fi = dh >> 1;
        #pragma unroll
        for (int j=0; j<4; ++j){
          const float o = acc[qi][db][j] * lb[j];
          const float oth = __shfl_xor(o, 1);   // partner d = dh^1 (lane c^1)
          const int lseq = qb*128 + w*32 + qi*16 + gb + j;
          const float2 mrow = *(const float2*)(MO + (size_t)lseq*64 + fi*4 + r*2);
          const float y = mrow.x*(r ? oth : o) + mrow.y*(r ? o : oth);
          AO[((size_t)(bix*1024 + lseq))*768 + hh*32 + dh] = f2bf(y);
        }
      }
    }
  }
}

extern "C" void kernel_launch(void* const* d_in, const int* in_sizes, int n_in,
                              void* d_out, int out_size, void* d_ws, size_t ws_size,
                              hipStream_t stream)
{
  (void)in_sizes; (void)n_in; (void)out_size; (void)ws_size;
  const float* x    = (const float*)d_in[0];
  const float* Wqkv = (const float*)d_in[1];
  const float* bqkv = (const float*)d_in[2];
  const float* Wo   = (const float*)d_in[3];
  const float* bo   = (const float*)d_in[4];
  const float* mq   = (const float*)d_in[5];
  const float* mk   = (const float*)d_in[6];
  const float* mv   = (const float*)d_in[7];
  const float* mo   = (const float*)d_in[8];
  float* out = (float*)d_out;

  const size_t NX   = (size_t)16*1024*768;     // 12.58M
  const size_t NWQ  = (size_t)2304*768;        // 1.77M
  const size_t NWO  = (size_t)768*768;         // 0.59M
  const size_t SQ   = (size_t)384*1024*32;     // per-tensor q/k/v elements

  // ws layout (~105.5 MB peak; ao aliases xb — xb dead after GEMM1, ao born after)
  u16* xb   = (u16*)d_ws;          // bf16 x            [16384][768]
  u16* wqb  = xb  + NX;            // bf16 W_qkv        [2304][768]
  u16* wob  = wqb + NWQ;           // bf16 W_o          [768][768]
  u16* q_l  = wob + NWO;           // [head][l][32]
  u16* k_l  = q_l + SQ;            // [head][l][32]
  u16* vT   = k_l + SQ;            // [head][32][l]
  u16* ao   = xb;                  // [b*l][768] bf16 (aliases xb)

  hipLaunchKernelGGL(conv_f2b, dim3(2048), dim3(256), 0, stream,
                     (const f32x4*)x, (u16x4*)xb, (int)(NX/4));
  hipLaunchKernelGGL(conv_f2b, dim3(1024), dim3(256), 0, stream,
                     (const f32x4*)Wqkv, (u16x4*)wqb, (int)(NWQ/4));
  hipLaunchKernelGGL(conv_f2b, dim3(512), dim3(256), 0, stream,
                     (const f32x4*)Wo, (u16x4*)wob, (int)(NWO/4));

  hipLaunchKernelGGL((gta_gemm<2304,0>), dim3(2304), dim3(256), 0, stream,
                     xb, wqb, bqkv, q_l, k_l, vT, (float*)nullptr, mq, mk, mv);
  hipLaunchKernelGGL(gta_attn, dim3(1536), dim3(256), 0, stream,
                     q_l, k_l, vT, mo, ao);
  hipLaunchKernelGGL((gta_gemm<768,1>), dim3(768), dim3(256), 0, stream,
                     ao, wob, bo, (u16*)nullptr, (u16*)nullptr, (u16*)nullptr, out,
                     (const float*)nullptr, (const float*)nullptr, (const float*)nullptr);
}